// Round 4
// baseline (326.722 us; speedup 1.0000x reference)
//
#include <hip/hip_runtime.h>

#define TT    524288
#define CHUNK 512
#define NCH   (TT / CHUNK)     // 1024 chunks
#define SUB   64               // subtile rows
#define NSUB  (CHUNK / SUB)    // 8

typedef __attribute__((ext_vector_type(8))) short short8;
typedef __attribute__((ext_vector_type(4))) float f32x4;

__device__ __forceinline__ unsigned short f2bf(float f) {
    union { float f; unsigned u; } v; v.f = f;
    unsigned r = v.u + 0x7FFFu + ((v.u >> 16) & 1u);   // RTNE
    return (unsigned short)(r >> 16);
}
// pack (a,b) -> bf16(a) | bf16(b)<<16
__device__ __forceinline__ unsigned packbf2(float a, float b) {
    union { float f; unsigned u; } va, vb; va.f = a; vb.f = b;
    unsigned ra = va.u + 0x7FFFu + ((va.u >> 16) & 1u);
    unsigned rb = vb.u + 0x7FFFu + ((vb.u >> 16) & 1u);
    return (ra >> 16) | (rb & 0xFFFF0000u);
}
__device__ __forceinline__ float2 unpackbf2(unsigned w) {
    union { unsigned u; float f; } a, b;
    a.u = w << 16; b.u = w & 0xFFFF0000u;
    return make_float2(a.f, b.f);
}
__device__ __forceinline__ float sigf(float v) {
    return __builtin_amdgcn_rcpf(1.0f + __expf(-v));   // v_exp + v_rcp
}

union U8 { uint4 u4; short8 s8; };

// ============================================================================
// Phase A v3: one block = one chunk (512 rows). Wave w owns subtiles {w, w+4}.
// MFMA A-frags direct from global (f32->bf16 in-register); sigmoid; pack;
// register export to abg. NEW: band maps computed fully in registers via a
// per-lane 4-row fold + ordered shfl_xor(16/32) tree -> the abw LDS transpose,
// its lgkm drains, and the serial 16-step ds-fold are deleted.
// LDS = 35.8 KB -> 4 blocks/CU (was 3). Zero barriers in the main loop.
// ============================================================================
__global__ __launch_bounds__(256, 4)
void aphase(const float* __restrict__ x, const float* __restrict__ W1,
            const float* __restrict__ B1,
            float* __restrict__ Aout, float* __restrict__ Bout,
            uint4* __restrict__ abg)
{
    __shared__ __align__(16) short W1t[128 * 72];   // W1^T bf16 [n][k] 18.4KB
    __shared__ float    B1s[128];
    __shared__ float    segA[32 * 66], segB[32 * 66]; // band maps 16.9KB

    const int tid  = threadIdx.x;
    const int c    = blockIdx.x;
    const int wave = tid >> 6;
    const int lane = tid & 63;
    const int quad = lane >> 4;
    const int lr   = lane & 15;

    for (int i = tid; i < 2048; i += 256) {
        float4 w4 = ((const float4*)W1)[i];
        int k = i >> 5, n0 = (i & 31) * 4;
        W1t[(n0 + 0) * 72 + k] = (short)f2bf(w4.x);
        W1t[(n0 + 1) * 72 + k] = (short)f2bf(w4.y);
        W1t[(n0 + 2) * 72 + k] = (short)f2bf(w4.z);
        W1t[(n0 + 3) * 72 + k] = (short)f2bf(w4.w);
    }
    if (tid < 128) B1s[tid] = B1[tid];
    __syncthreads();   // staging barrier (1 of 2)

    // hoist bias to registers
    float bb[8];
    #pragma unroll
    for (int j = 0; j < 8; ++j) bb[j] = B1s[j * 16 + lr];

    const float* xbase = x + (size_t)c * CHUNK * 64;

    // fragment load address for (subtile ss, row-tile rt): 4x float4 per lane
    #define FRAGP(ss, rt) ((const float4*)(xbase + (size_t)(((ss) * 64 + (rt) * 16 + lr)) * 64) + quad * 2)

    // prologue: load fi=0
    const float4* p0 = FRAGP(wave, 0);
    float4 c0 = p0[0], c1 = p0[1], c2 = p0[8], c3 = p0[9];

    const bool h1 = (quad & 1) != 0;   // hi half of the quad pair
    const bool h2 = (quad & 2) != 0;   // hi half of the 16-row block

    for (int fi = 0; fi < 8; ++fi) {
        const int ss = (fi < 4) ? wave : (wave + 4);
        const int rt = fi & 3;

        // ---- prefetch next fragment (full-body latency window) ----
        float4 n0, n1, n2, n3;
        if (fi < 7) {
            const int ns = (fi + 1 < 4) ? wave : (wave + 4);
            const int nr = (fi + 1) & 3;
            const float4* np = FRAGP(ns, nr);
            n0 = np[0]; n1 = np[1]; n2 = np[8]; n3 = np[9];
        }

        // ---- convert current 16-row tile to bf16 A-frags ----
        U8 ua, ub;
        ua.u4 = make_uint4(packbf2(c0.x, c0.y), packbf2(c0.z, c0.w),
                           packbf2(c1.x, c1.y), packbf2(c1.z, c1.w));
        ub.u4 = make_uint4(packbf2(c2.x, c2.y), packbf2(c2.z, c2.w),
                           packbf2(c3.x, c3.y), packbf2(c3.z, c3.w));
        const short8 a0 = ua.s8, a1 = ub.s8;

        // ---- MFMA 16 rows x 128 cols ----
        f32x4 acc[8];
        #pragma unroll
        for (int j = 0; j < 8; ++j) {
            acc[j][0] = bb[j]; acc[j][1] = bb[j]; acc[j][2] = bb[j]; acc[j][3] = bb[j];
        }
        #pragma unroll
        for (int j = 0; j < 8; ++j) {
            const short8 b0 = *(const short8*)&W1t[(j * 16 + lr) * 72 + quad * 8];
            const short8 b1 = *(const short8*)&W1t[(j * 16 + lr) * 72 + quad * 8 + 32];
            acc[j] = __builtin_amdgcn_mfma_f32_16x16x32_bf16(a0, b0, acc[j], 0, 0, 0);
            acc[j] = __builtin_amdgcn_mfma_f32_16x16x32_bf16(a1, b1, acc[j], 0, 0, 0);
        }

        // ---- sigmoid; a=l*r, b=1-l; pack ----
        unsigned pk[4][4];
        #pragma unroll
        for (int j = 0; j < 4; ++j) {
            #pragma unroll
            for (int r = 0; r < 4; ++r) {
                float hl = sigf(acc[j][r]);
                float hr = sigf(acc[j + 4][r]);
                pk[j][r] = packbf2(hl * hr, 1.0f - hl);
            }
        }

        // ---- export ab directly from registers (rows quad*4+r are thread-local) ----
        {
            uint4* dstq = abg + ((size_t)((c * NSUB + ss) * 16 + rt * 4 + quad)) * 64 + lr;
            #pragma unroll
            for (int j = 0; j < 4; ++j)
                dstq[j * 16] = make_uint4(pk[j][0], pk[j][1], pk[j][2], pk[j][3]);
        }

        // ---- band map fully in registers ----
        // per-lane: fold my 4 rows (row order) for each of my 4 channels
        float Aa[4], Ba[4];
        #pragma unroll
        for (int j = 0; j < 4; ++j) {
            float A = 1.0f, Bv = 0.0f;
            #pragma unroll
            for (int r = 0; r < 4; ++r) {
                float2 f = unpackbf2(pk[j][r]);
                Bv = fmaf(f.x, Bv, f.y); A *= f.x;
            }
            Aa[j] = A; Ba[j] = Bv;
        }
        // ordered tree over quads: (q0,q1),(q2,q3) then (q01,q23).
        // combine(hi,lo): A = A_hi*A_lo (commutative, bit-identical both sides),
        //                 B = fmaf(A_hi, B_lo, B_hi).
        #pragma unroll
        for (int j = 0; j < 4; ++j) {
            float Ap = __shfl_xor(Aa[j], 16);
            float Bp = __shfl_xor(Ba[j], 16);
            float Ahi = h1 ? Aa[j] : Ap;
            float Blo = h1 ? Bp    : Ba[j];
            float Bhi = h1 ? Ba[j] : Bp;
            Aa[j] *= Ap;
            Ba[j] = fmaf(Ahi, Blo, Bhi);

            Ap = __shfl_xor(Aa[j], 32);
            Bp = __shfl_xor(Ba[j], 32);
            Ahi = h2 ? Aa[j] : Ap;
            Blo = h2 ? Bp    : Ba[j];
            Bhi = h2 ? Ba[j] : Bp;
            Aa[j] *= Ap;
            Ba[j] = fmaf(Ahi, Blo, Bhi);
        }
        // lane (quad,lr) stores channel quad*16+lr == lane (compile-time select)
        const float Asel = (quad == 0) ? Aa[0] : (quad == 1) ? Aa[1]
                         : (quad == 2) ? Aa[2] : Aa[3];
        const float Bsel = (quad == 0) ? Ba[0] : (quad == 1) ? Ba[1]
                         : (quad == 2) ? Ba[2] : Ba[3];
        const int band = ss * 4 + rt;
        segA[band * 66 + lane] = Asel;
        segB[band * 66 + lane] = Bsel;

        if (fi < 7) { c0 = n0; c1 = n1; c2 = n2; c3 = n3; }
    }
    #undef FRAGP

    __syncthreads();   // (2 of 2)
    if (tid < 64) {
        float sA = 1.0f, sB = 0.0f;
        // serial fold over all 32 bands in row order
        for (int b = 0; b < 32; ++b) {
            float A2 = segA[b * 66 + tid], B2v = segB[b * 66 + tid];
            sB = fmaf(A2, sB, B2v); sA *= A2;
        }
        Aout[c * 64 + tid] = sA; Bout[c * 64 + tid] = sB;
    }
}

// ============================================================================
// Carry scan across 1024 chunk maps: 16 parallel segments of 64 (1024 thr).
// ============================================================================
__global__ void carry_scan(const float* __restrict__ Aar, const float* __restrict__ Bar,
                           float* __restrict__ carry)
{
    __shared__ float sA[16 * 66], sB[16 * 66];
    const int tid = threadIdx.x;
    const int ch = tid & 63, seg = tid >> 6;       // 16 segments
    const int c0 = seg * (NCH / 16);

    float A = 1.0f, B = 0.0f;
    #pragma unroll 8
    for (int i = 0; i < NCH / 16; ++i) {
        const int idx = c0 + i;
        const float a = Aar[idx * 64 + ch];
        const float b = Bar[idx * 64 + ch];
        B = fmaf(a, B, b); A *= a;
    }
    sA[seg * 66 + ch] = A;
    sB[seg * 66 + ch] = B;
    __syncthreads();

    float u = 0.0f;
    #pragma unroll
    for (int q = 0; q < 15; ++q)
        if (q < seg) u = fmaf(sA[q * 66 + ch], u, sB[q * 66 + ch]);
    #pragma unroll 8
    for (int i = 0; i < NCH / 16; ++i) {
        const int idx = c0 + i;
        carry[idx * 64 + ch] = u;
        u = fmaf(Aar[idx * 64 + ch], u, Bar[idx * 64 + ch]);
    }
}

// ============================================================================
// Phase E v3: prefetch moved to right after ESTEP, loading DIRECTLY into
// r0..r3 (no n* copies -> ~16 fewer VGPRs); __launch_bounds__(256,6).
// One barrier per subtile; parity double-buffered seg/ucur.
// ============================================================================
__global__ __launch_bounds__(256, 6)
void ephase(const uint4* __restrict__ abg, const float* __restrict__ carry,
            const float* __restrict__ W2, const float* __restrict__ B2,
            float* __restrict__ out)
{
    __shared__ __align__(16) short Zs[SUB * 72];       // z bf16 [m][k] 9.2KB
    __shared__ float segA[2 * 4 * 66], segB[2 * 4 * 66];
    __shared__ __align__(16) short W2t[32 * 72];       // W2^T bf16 [n][k]
    __shared__ float B2s[32];
    __shared__ float ucur[2 * 64];

    const int tid  = threadIdx.x;
    const int c    = blockIdx.x;
    const int wave = tid >> 6;
    const int lane = tid & 63;
    const int quad = lane >> 4;
    const int lr   = lane & 15;

    for (int i = tid; i < 512; i += 256) {
        float4 w4 = ((const float4*)W2)[i];
        int k = i >> 3, n0 = (i & 7) * 4;
        W2t[(n0 + 0) * 72 + k] = (short)f2bf(w4.x);
        W2t[(n0 + 1) * 72 + k] = (short)f2bf(w4.y);
        W2t[(n0 + 2) * 72 + k] = (short)f2bf(w4.z);
        W2t[(n0 + 3) * 72 + k] = (short)f2bf(w4.w);
    }
    if (tid < 32) B2s[tid] = B2[tid];
    if (tid < 64) ucur[tid] = carry[c * 64 + tid];     // ucur[0][*]
    // first reads of all staged LDS happen after the s=0 barrier below.

    const uint4* ag = abg + (size_t)c * (NSUB * 16 * 64);
    uint4 r0 = ag[(wave * 4 + 0) * 64 + lane];
    uint4 r1 = ag[(wave * 4 + 1) * 64 + lane];
    uint4 r2 = ag[(wave * 4 + 2) * 64 + lane];
    uint4 r3 = ag[(wave * 4 + 3) * 64 + lane];

    for (int s = 0; s < NSUB; ++s) {
        const int pb = (s & 1) * 264;                  // seg buffer parity

        // ---- compose own 16 rows from registers ----
        float A = 1.0f, Bv = 0.0f; float2 f;
#define CSTEP(W) { f = unpackbf2(W); Bv = fmaf(f.x, Bv, f.y); A *= f.x; }
        CSTEP(r0.x) CSTEP(r0.y) CSTEP(r0.z) CSTEP(r0.w)
        CSTEP(r1.x) CSTEP(r1.y) CSTEP(r1.z) CSTEP(r1.w)
        CSTEP(r2.x) CSTEP(r2.y) CSTEP(r2.z) CSTEP(r2.w)
        CSTEP(r3.x) CSTEP(r3.y) CSTEP(r3.z) CSTEP(r3.w)
#undef CSTEP
        segA[pb + wave * 66 + lane] = A;
        segB[pb + wave * 66 + lane] = Bv;
        __syncthreads();   // the only barrier per subtile

        // ---- per-wave prefix from carry-in ----
        float u = ucur[(s & 1) * 64 + lane];
        #pragma unroll
        for (int q = 0; q < 3; ++q)
            if (q < wave) u = fmaf(segA[pb + q * 66 + lane], u, segB[pb + q * 66 + lane]);

        // ---- emit z into own 16-row band of Zs ----
        int t = 0;
#define ESTEP(W) { Zs[(wave * 16 + t) * 72 + lane] = (short)f2bf(u); \
                   f = unpackbf2(W); u = fmaf(f.x, u, f.y); ++t; }
        ESTEP(r0.x) ESTEP(r0.y) ESTEP(r0.z) ESTEP(r0.w)
        ESTEP(r1.x) ESTEP(r1.y) ESTEP(r1.z) ESTEP(r1.w)
        ESTEP(r2.x) ESTEP(r2.y) ESTEP(r2.z) ESTEP(r2.w)
        ESTEP(r3.x) ESTEP(r3.y) ESTEP(r3.z) ESTEP(r3.w)
#undef ESTEP
        if (wave == 3) ucur[((s + 1) & 1) * 64 + lane] = u;   // other parity

        // ---- prefetch next subtile DIRECTLY into r* (r* dead after ESTEP) ----
        if (s + 1 < NSUB) {
            const uint4* an = ag + (size_t)(s + 1) * (16 * 64);
            r0 = an[(wave * 4 + 0) * 64 + lane];
            r1 = an[(wave * 4 + 1) * 64 + lane];
            r2 = an[(wave * 4 + 2) * 64 + lane];
            r3 = an[(wave * 4 + 3) * 64 + lane];
        }

        // ---- out = Z @ W2 + B2 via MFMA (reads own band only) ----
        const short8 za0 = *(const short8*)&Zs[(wave * 16 + lr) * 72 + quad * 8];
        const short8 za1 = *(const short8*)&Zs[(wave * 16 + lr) * 72 + quad * 8 + 32];
        const size_t row0g = (size_t)c * CHUNK + (size_t)s * SUB;
        #pragma unroll
        for (int nt = 0; nt < 2; ++nt) {
            f32x4 cc;
            float b = B2s[nt * 16 + lr];
            cc[0] = b; cc[1] = b; cc[2] = b; cc[3] = b;
            const short8 b0 = *(const short8*)&W2t[(nt * 16 + lr) * 72 + quad * 8];
            const short8 b1 = *(const short8*)&W2t[(nt * 16 + lr) * 72 + quad * 8 + 32];
            cc = __builtin_amdgcn_mfma_f32_16x16x32_bf16(za0, b0, cc, 0, 0, 0);
            cc = __builtin_amdgcn_mfma_f32_16x16x32_bf16(za1, b1, cc, 0, 0, 0);
            #pragma unroll
            for (int r = 0; r < 4; ++r) {
                int m = wave * 16 + quad * 4 + r;
                out[(row0g + m) * 32 + nt * 16 + lr] = cc[r];
            }
        }
        // no trailing barrier: seg/ucur are parity double-buffered; Zs is
        // same-wave only; next overwrite of this parity is separated by the
        // next iteration's barrier.
    }
}

extern "C" void kernel_launch(void* const* d_in, const int* in_sizes, int n_in,
                              void* d_out, int out_size, void* d_ws, size_t ws_size,
                              hipStream_t stream)
{
    const float* x  = (const float*)d_in[0];
    const float* W1 = (const float*)d_in[1];
    const float* B1 = (const float*)d_in[2];
    const float* W2 = (const float*)d_in[3];
    const float* B2 = (const float*)d_in[4];
    float* out = (float*)d_out;

    float* Aar   = (float*)d_ws;            // NCH*64
    float* Bar   = Aar + NCH * 64;          // NCH*64
    float* carry = Bar + NCH * 64;          // NCH*64
    uint4* abg   = (uint4*)(carry + NCH * 64);  // T*64*4 B = 134.2 MB packed ab

    aphase<<<NCH, 256, 0, stream>>>(x, W1, B1, Aar, Bar, abg);
    carry_scan<<<1, 1024, 0, stream>>>(Aar, Bar, carry);
    ephase<<<NCH, 256, 0, stream>>>(abg, carry, W2, B2, out);
}

// Round 5
// 296.583 us; speedup vs baseline: 1.1016x; 1.1016x over previous
//
#include <hip/hip_runtime.h>

#define TT    524288
#define CHUNK 512
#define NCH   (TT / CHUNK)     // 1024 chunks
#define SUB   64               // subtile rows
#define NSUB  (CHUNK / SUB)    // 8

typedef __attribute__((ext_vector_type(8))) short short8;
typedef __attribute__((ext_vector_type(4))) float f32x4;

__device__ __forceinline__ unsigned short f2bf(float f) {
    union { float f; unsigned u; } v; v.f = f;
    unsigned r = v.u + 0x7FFFu + ((v.u >> 16) & 1u);   // RTNE
    return (unsigned short)(r >> 16);
}
// pack (a,b) -> bf16(a) | bf16(b)<<16
__device__ __forceinline__ unsigned packbf2(float a, float b) {
    union { float f; unsigned u; } va, vb; va.f = a; vb.f = b;
    unsigned ra = va.u + 0x7FFFu + ((va.u >> 16) & 1u);
    unsigned rb = vb.u + 0x7FFFu + ((vb.u >> 16) & 1u);
    return (ra >> 16) | (rb & 0xFFFF0000u);
}
__device__ __forceinline__ float2 unpackbf2(unsigned w) {
    union { unsigned u; float f; } a, b;
    a.u = w << 16; b.u = w & 0xFFFF0000u;
    return make_float2(a.f, b.f);
}
__device__ __forceinline__ float sigf(float v) {
    return __builtin_amdgcn_rcpf(1.0f + __expf(-v));   // v_exp + v_rcp
}

union U8 { uint4 u4; short8 s8; };

// ============================================================================
// Phase A v4: v3 structure (register band-map + ordered shfl_xor tree, zero
// loop barriers) with the SPILL REGRESSION fixed:
//  - __launch_bounds__(256,3): 84 VGPRs (v2-proven no-spill), 3 blocks/CU
//  - no n* prefetch copies: convert c* -> bf16 frags, then reload the NEXT
//    tile directly into c0..c3 (dead after conversion). Single fragment set.
// LDS = 35.8 KB.
// ============================================================================
__global__ __launch_bounds__(256, 3)
void aphase(const float* __restrict__ x, const float* __restrict__ W1,
            const float* __restrict__ B1,
            float* __restrict__ Aout, float* __restrict__ Bout,
            uint4* __restrict__ abg)
{
    __shared__ __align__(16) short W1t[128 * 72];   // W1^T bf16 [n][k] 18.4KB
    __shared__ float    B1s[128];
    __shared__ float    segA[32 * 66], segB[32 * 66]; // band maps 16.9KB

    const int tid  = threadIdx.x;
    const int c    = blockIdx.x;
    const int wave = tid >> 6;
    const int lane = tid & 63;
    const int quad = lane >> 4;
    const int lr   = lane & 15;

    for (int i = tid; i < 2048; i += 256) {
        float4 w4 = ((const float4*)W1)[i];
        int k = i >> 5, n0 = (i & 31) * 4;
        W1t[(n0 + 0) * 72 + k] = (short)f2bf(w4.x);
        W1t[(n0 + 1) * 72 + k] = (short)f2bf(w4.y);
        W1t[(n0 + 2) * 72 + k] = (short)f2bf(w4.z);
        W1t[(n0 + 3) * 72 + k] = (short)f2bf(w4.w);
    }
    if (tid < 128) B1s[tid] = B1[tid];
    __syncthreads();   // staging barrier (1 of 2)

    // hoist bias to registers
    float bb[8];
    #pragma unroll
    for (int j = 0; j < 8; ++j) bb[j] = B1s[j * 16 + lr];

    const float* xbase = x + (size_t)c * CHUNK * 64;

    // fragment load address for (subtile ss, row-tile rt): 4x float4 per lane
    #define FRAGP(ss, rt) ((const float4*)(xbase + (size_t)(((ss) * 64 + (rt) * 16 + lr)) * 64) + quad * 2)

    // prologue: load fi=0
    const float4* p0 = FRAGP(wave, 0);
    float4 c0 = p0[0], c1 = p0[1], c2 = p0[8], c3 = p0[9];

    const bool h1 = (quad & 1) != 0;   // hi half of the quad pair
    const bool h2 = (quad & 2) != 0;   // hi half of the 16-row block

    for (int fi = 0; fi < 8; ++fi) {
        const int ss = (fi < 4) ? wave : (wave + 4);
        const int rt = fi & 3;

        // ---- convert current 16-row tile to bf16 A-frags (frees c0..c3) ----
        U8 ua, ub;
        ua.u4 = make_uint4(packbf2(c0.x, c0.y), packbf2(c0.z, c0.w),
                           packbf2(c1.x, c1.y), packbf2(c1.z, c1.w));
        ub.u4 = make_uint4(packbf2(c2.x, c2.y), packbf2(c2.z, c2.w),
                           packbf2(c3.x, c3.y), packbf2(c3.z, c3.w));
        const short8 a0 = ua.s8, a1 = ub.s8;

        // ---- immediately reload NEXT tile into c* (full-body latency window,
        //      no extra registers) ----
        if (fi < 7) {
            const int ns = (fi + 1 < 4) ? wave : (wave + 4);
            const int nr = (fi + 1) & 3;
            const float4* np = FRAGP(ns, nr);
            c0 = np[0]; c1 = np[1]; c2 = np[8]; c3 = np[9];
        }

        // ---- MFMA 16 rows x 128 cols ----
        f32x4 acc[8];
        #pragma unroll
        for (int j = 0; j < 8; ++j) {
            acc[j][0] = bb[j]; acc[j][1] = bb[j]; acc[j][2] = bb[j]; acc[j][3] = bb[j];
        }
        #pragma unroll
        for (int j = 0; j < 8; ++j) {
            const short8 b0 = *(const short8*)&W1t[(j * 16 + lr) * 72 + quad * 8];
            const short8 b1 = *(const short8*)&W1t[(j * 16 + lr) * 72 + quad * 8 + 32];
            acc[j] = __builtin_amdgcn_mfma_f32_16x16x32_bf16(a0, b0, acc[j], 0, 0, 0);
            acc[j] = __builtin_amdgcn_mfma_f32_16x16x32_bf16(a1, b1, acc[j], 0, 0, 0);
        }

        // ---- sigmoid; a=l*r, b=1-l; pack ----
        unsigned pk[4][4];
        #pragma unroll
        for (int j = 0; j < 4; ++j) {
            #pragma unroll
            for (int r = 0; r < 4; ++r) {
                float hl = sigf(acc[j][r]);
                float hr = sigf(acc[j + 4][r]);
                pk[j][r] = packbf2(hl * hr, 1.0f - hl);
            }
        }

        // ---- export ab directly from registers (rows quad*4+r are thread-local) ----
        {
            uint4* dstq = abg + ((size_t)((c * NSUB + ss) * 16 + rt * 4 + quad)) * 64 + lr;
            #pragma unroll
            for (int j = 0; j < 4; ++j)
                dstq[j * 16] = make_uint4(pk[j][0], pk[j][1], pk[j][2], pk[j][3]);
        }

        // ---- band map fully in registers ----
        // per-lane: fold my 4 rows (row order) for each of my 4 channels
        float Aa[4], Ba[4];
        #pragma unroll
        for (int j = 0; j < 4; ++j) {
            float A = 1.0f, Bv = 0.0f;
            #pragma unroll
            for (int r = 0; r < 4; ++r) {
                float2 f = unpackbf2(pk[j][r]);
                Bv = fmaf(f.x, Bv, f.y); A *= f.x;
            }
            Aa[j] = A; Ba[j] = Bv;
        }
        // ordered tree over quads: (q0,q1),(q2,q3) then (q01,q23).
        // combine(hi,lo): A = A_hi*A_lo; B = fmaf(A_hi, B_lo, B_hi).
        #pragma unroll
        for (int j = 0; j < 4; ++j) {
            float Ap = __shfl_xor(Aa[j], 16);
            float Bp = __shfl_xor(Ba[j], 16);
            float Ahi = h1 ? Aa[j] : Ap;
            float Blo = h1 ? Bp    : Ba[j];
            float Bhi = h1 ? Ba[j] : Bp;
            Aa[j] *= Ap;
            Ba[j] = fmaf(Ahi, Blo, Bhi);

            Ap = __shfl_xor(Aa[j], 32);
            Bp = __shfl_xor(Ba[j], 32);
            Ahi = h2 ? Aa[j] : Ap;
            Blo = h2 ? Bp    : Ba[j];
            Bhi = h2 ? Ba[j] : Bp;
            Aa[j] *= Ap;
            Ba[j] = fmaf(Ahi, Blo, Bhi);
        }
        // lane (quad,lr) stores channel quad*16+lr == lane (compile-time select)
        const float Asel = (quad == 0) ? Aa[0] : (quad == 1) ? Aa[1]
                         : (quad == 2) ? Aa[2] : Aa[3];
        const float Bsel = (quad == 0) ? Ba[0] : (quad == 1) ? Ba[1]
                         : (quad == 2) ? Ba[2] : Ba[3];
        const int band = ss * 4 + rt;
        segA[band * 66 + lane] = Asel;
        segB[band * 66 + lane] = Bsel;
    }
    #undef FRAGP

    __syncthreads();   // (2 of 2)
    if (tid < 64) {
        float sA = 1.0f, sB = 0.0f;
        // serial fold over all 32 bands in row order
        for (int b = 0; b < 32; ++b) {
            float A2 = segA[b * 66 + tid], B2v = segB[b * 66 + tid];
            sB = fmaf(A2, sB, B2v); sA *= A2;
        }
        Aout[c * 64 + tid] = sA; Bout[c * 64 + tid] = sB;
    }
}

// ============================================================================
// Carry scan across 1024 chunk maps: 16 parallel segments of 64 (1024 thr).
// ============================================================================
__global__ void carry_scan(const float* __restrict__ Aar, const float* __restrict__ Bar,
                           float* __restrict__ carry)
{
    __shared__ float sA[16 * 66], sB[16 * 66];
    const int tid = threadIdx.x;
    const int ch = tid & 63, seg = tid >> 6;       // 16 segments
    const int c0 = seg * (NCH / 16);

    float A = 1.0f, B = 0.0f;
    #pragma unroll 8
    for (int i = 0; i < NCH / 16; ++i) {
        const int idx = c0 + i;
        const float a = Aar[idx * 64 + ch];
        const float b = Bar[idx * 64 + ch];
        B = fmaf(a, B, b); A *= a;
    }
    sA[seg * 66 + ch] = A;
    sB[seg * 66 + ch] = B;
    __syncthreads();

    float u = 0.0f;
    #pragma unroll
    for (int q = 0; q < 15; ++q)
        if (q < seg) u = fmaf(sA[q * 66 + ch], u, sB[q * 66 + ch]);
    #pragma unroll 8
    for (int i = 0; i < NCH / 16; ++i) {
        const int idx = c0 + i;
        carry[idx * 64 + ch] = u;
        u = fmaf(Aar[idx * 64 + ch], u, Bar[idx * 64 + ch]);
    }
}

// ============================================================================
// Phase E v4: revert to the v2-proven shape — __launch_bounds__(256,4)
// (64 VGPRs, no spill), top-of-loop prefetch into n* (full-body latency
// window). One barrier per subtile; parity double-buffered seg/ucur.
// ============================================================================
__global__ __launch_bounds__(256, 4)
void ephase(const uint4* __restrict__ abg, const float* __restrict__ carry,
            const float* __restrict__ W2, const float* __restrict__ B2,
            float* __restrict__ out)
{
    __shared__ __align__(16) short Zs[SUB * 72];       // z bf16 [m][k] 9.2KB
    __shared__ float segA[2 * 4 * 66], segB[2 * 4 * 66];
    __shared__ __align__(16) short W2t[32 * 72];       // W2^T bf16 [n][k]
    __shared__ float B2s[32];
    __shared__ float ucur[2 * 64];

    const int tid  = threadIdx.x;
    const int c    = blockIdx.x;
    const int wave = tid >> 6;
    const int lane = tid & 63;
    const int quad = lane >> 4;
    const int lr   = lane & 15;

    for (int i = tid; i < 512; i += 256) {
        float4 w4 = ((const float4*)W2)[i];
        int k = i >> 3, n0 = (i & 7) * 4;
        W2t[(n0 + 0) * 72 + k] = (short)f2bf(w4.x);
        W2t[(n0 + 1) * 72 + k] = (short)f2bf(w4.y);
        W2t[(n0 + 2) * 72 + k] = (short)f2bf(w4.z);
        W2t[(n0 + 3) * 72 + k] = (short)f2bf(w4.w);
    }
    if (tid < 32) B2s[tid] = B2[tid];
    if (tid < 64) ucur[tid] = carry[c * 64 + tid];     // ucur[0][*]
    // first reads of all staged LDS happen after the s=0 barrier below.

    const uint4* ag = abg + (size_t)c * (NSUB * 16 * 64);
    uint4 r0 = ag[(wave * 4 + 0) * 64 + lane];
    uint4 r1 = ag[(wave * 4 + 1) * 64 + lane];
    uint4 r2 = ag[(wave * 4 + 2) * 64 + lane];
    uint4 r3 = ag[(wave * 4 + 3) * 64 + lane];

    for (int s = 0; s < NSUB; ++s) {
        const int pb = (s & 1) * 264;                  // seg buffer parity

        // ---- issue next subtile's ab loads FIRST (full-body latency window) ----
        uint4 n0, n1, n2, n3;
        if (s + 1 < NSUB) {
            const uint4* an = ag + (size_t)(s + 1) * (16 * 64);
            n0 = an[(wave * 4 + 0) * 64 + lane];
            n1 = an[(wave * 4 + 1) * 64 + lane];
            n2 = an[(wave * 4 + 2) * 64 + lane];
            n3 = an[(wave * 4 + 3) * 64 + lane];
        }

        // ---- compose own 16 rows from registers ----
        float A = 1.0f, Bv = 0.0f; float2 f;
#define CSTEP(W) { f = unpackbf2(W); Bv = fmaf(f.x, Bv, f.y); A *= f.x; }
        CSTEP(r0.x) CSTEP(r0.y) CSTEP(r0.z) CSTEP(r0.w)
        CSTEP(r1.x) CSTEP(r1.y) CSTEP(r1.z) CSTEP(r1.w)
        CSTEP(r2.x) CSTEP(r2.y) CSTEP(r2.z) CSTEP(r2.w)
        CSTEP(r3.x) CSTEP(r3.y) CSTEP(r3.z) CSTEP(r3.w)
#undef CSTEP
        segA[pb + wave * 66 + lane] = A;
        segB[pb + wave * 66 + lane] = Bv;
        __syncthreads();   // the only barrier per subtile

        // ---- per-wave prefix from carry-in ----
        float u = ucur[(s & 1) * 64 + lane];
        #pragma unroll
        for (int q = 0; q < 3; ++q)
            if (q < wave) u = fmaf(segA[pb + q * 66 + lane], u, segB[pb + q * 66 + lane]);

        // ---- emit z into own 16-row band of Zs ----
        int t = 0;
#define ESTEP(W) { Zs[(wave * 16 + t) * 72 + lane] = (short)f2bf(u); \
                   f = unpackbf2(W); u = fmaf(f.x, u, f.y); ++t; }
        ESTEP(r0.x) ESTEP(r0.y) ESTEP(r0.z) ESTEP(r0.w)
        ESTEP(r1.x) ESTEP(r1.y) ESTEP(r1.z) ESTEP(r1.w)
        ESTEP(r2.x) ESTEP(r2.y) ESTEP(r2.z) ESTEP(r2.w)
        ESTEP(r3.x) ESTEP(r3.y) ESTEP(r3.z) ESTEP(r3.w)
#undef ESTEP
        if (wave == 3) ucur[((s + 1) & 1) * 64 + lane] = u;   // other parity

        // ---- out = Z @ W2 + B2 via MFMA (reads own band only) ----
        const short8 za0 = *(const short8*)&Zs[(wave * 16 + lr) * 72 + quad * 8];
        const short8 za1 = *(const short8*)&Zs[(wave * 16 + lr) * 72 + quad * 8 + 32];
        const size_t row0g = (size_t)c * CHUNK + (size_t)s * SUB;
        #pragma unroll
        for (int nt = 0; nt < 2; ++nt) {
            f32x4 cc;
            float b = B2s[nt * 16 + lr];
            cc[0] = b; cc[1] = b; cc[2] = b; cc[3] = b;
            const short8 b0 = *(const short8*)&W2t[(nt * 16 + lr) * 72 + quad * 8];
            const short8 b1 = *(const short8*)&W2t[(nt * 16 + lr) * 72 + quad * 8 + 32];
            cc = __builtin_amdgcn_mfma_f32_16x16x32_bf16(za0, b0, cc, 0, 0, 0);
            cc = __builtin_amdgcn_mfma_f32_16x16x32_bf16(za1, b1, cc, 0, 0, 0);
            #pragma unroll
            for (int r = 0; r < 4; ++r) {
                int m = wave * 16 + quad * 4 + r;
                out[(row0g + m) * 32 + nt * 16 + lr] = cc[r];
            }
        }
        if (s + 1 < NSUB) { r0 = n0; r1 = n1; r2 = n2; r3 = n3; }
        // no trailing barrier: seg/ucur are parity double-buffered; Zs is
        // same-wave only; next overwrite of this parity is separated by the
        // next iteration's barrier.
    }
}

extern "C" void kernel_launch(void* const* d_in, const int* in_sizes, int n_in,
                              void* d_out, int out_size, void* d_ws, size_t ws_size,
                              hipStream_t stream)
{
    const float* x  = (const float*)d_in[0];
    const float* W1 = (const float*)d_in[1];
    const float* B1 = (const float*)d_in[2];
    const float* W2 = (const float*)d_in[3];
    const float* B2 = (const float*)d_in[4];
    float* out = (float*)d_out;

    float* Aar   = (float*)d_ws;            // NCH*64
    float* Bar   = Aar + NCH * 64;          // NCH*64
    float* carry = Bar + NCH * 64;          // NCH*64
    uint4* abg   = (uint4*)(carry + NCH * 64);  // T*64*4 B = 134.2 MB packed ab

    aphase<<<NCH, 256, 0, stream>>>(x, W1, B1, Aar, Bar, abg);
    carry_scan<<<1, 1024, 0, stream>>>(Aar, Bar, carry);
    ephase<<<NCH, 256, 0, stream>>>(abg, carry, W2, B2, out);
}